// Round 2
// baseline (214.474 us; speedup 1.0000x reference)
//
#include <hip/hip_runtime.h>
#include <hip/hip_bf16.h>
#include <stdint.h>

typedef unsigned short u16;
typedef __bf16 bf16x8 __attribute__((ext_vector_type(8)));
typedef float f32x4 __attribute__((ext_vector_type(4)));

// E=8, D=512, H=256, T=64, B=16384

__device__ __forceinline__ void glds16(const void* g, void* l) {
  __builtin_amdgcn_global_load_lds(
      (const __attribute__((address_space(1))) unsigned int*)g,
      (__attribute__((address_space(3))) unsigned int*)l, 16, 0, 0);
}

__device__ __forceinline__ u16 f2bf(float f) {
  unsigned int u = __builtin_bit_cast(unsigned int, f);
  u += 0x7fffu + ((u >> 16) & 1u);   // RNE (finite inputs)
  return (u16)(u >> 16);
}

// ---------------- prep: weight conversion only ----------------
// bx 0..511:  We (1048576 elems) -> We_bf
// bx 512..519: Wt (16384) -> Wt_bf
// bx 520..521: Wg (4096) -> Wg_hi + Wg_lo (hi/lo bf16 split for f32-accurate gate MFMA)
__global__ __launch_bounds__(256) void prep_w(
    const float* __restrict__ We, const float* __restrict__ Wt,
    const float* __restrict__ Wg,
    u16* __restrict__ We_bf, u16* __restrict__ Wt_bf,
    u16* __restrict__ Wg_hi, u16* __restrict__ Wg_lo) {
  const int bx = blockIdx.x;
  if (bx < 520) {
    const float* src; u16* dst;
    if (bx < 512) { int base = bx * 2048 + threadIdx.x * 8; src = We + base; dst = We_bf + base; }
    else { int base = (bx - 512) * 2048 + threadIdx.x * 8; src = Wt + base; dst = Wt_bf + base; }
    float4 a = *(const float4*)src;
    float4 b = *(const float4*)(src + 4);
    uint4 o;
    o.x = (unsigned)f2bf(a.x) | ((unsigned)f2bf(a.y) << 16);
    o.y = (unsigned)f2bf(a.z) | ((unsigned)f2bf(a.w) << 16);
    o.z = (unsigned)f2bf(b.x) | ((unsigned)f2bf(b.y) << 16);
    o.w = (unsigned)f2bf(b.z) | ((unsigned)f2bf(b.w) << 16);
    *(uint4*)dst = o;
  } else {
    int base = (bx - 520) * 2048 + threadIdx.x * 8;
    float x[8];
    float4 a = *(const float4*)(Wg + base);
    float4 b = *(const float4*)(Wg + base + 4);
    x[0]=a.x; x[1]=a.y; x[2]=a.z; x[3]=a.w; x[4]=b.x; x[5]=b.y; x[6]=b.z; x[7]=b.w;
    u16 h[8], l[8];
#pragma unroll
    for (int j = 0; j < 8; j++) {
      h[j] = f2bf(x[j]);
      float hf = __builtin_bit_cast(float, ((unsigned)h[j]) << 16);
      l[j] = f2bf(x[j] - hf);
    }
    uint4 oh, ol;
    oh.x = (unsigned)h[0] | ((unsigned)h[1] << 16);
    oh.y = (unsigned)h[2] | ((unsigned)h[3] << 16);
    oh.z = (unsigned)h[4] | ((unsigned)h[5] << 16);
    oh.w = (unsigned)h[6] | ((unsigned)h[7] << 16);
    ol.x = (unsigned)l[0] | ((unsigned)l[1] << 16);
    ol.y = (unsigned)l[2] | ((unsigned)l[3] << 16);
    ol.z = (unsigned)l[4] | ((unsigned)l[5] << 16);
    ol.w = (unsigned)l[6] | ((unsigned)l[7] << 16);
    *(uint4*)(Wg_hi + base) = oh;
    *(uint4*)(Wg_lo + base) = ol;
  }
}

// stage one B chunk (256 h-rows x 128 k, bf16) into ldsbuf via glds16,
// 16B-granule xor-swizzled source (slot s of row n holds granule (s&8)|((s&7)^(n&7)))
__device__ __forceinline__ void stage_chunk(const u16* __restrict__ We_bf,
                                            u16* ldsbuf, int t, int tid) {
  const int e_ = t >> 2, kc_ = t & 3;
  const u16* src = We_bf + (e_ << 17) + (kc_ << 7);
#pragma unroll
  for (int r = 0; r < 8; r++) {
    int gi = r * 512 + tid;             // 0..4095
    int n = gi >> 4, s = gi & 15;
    int g = (s & 8) | ((s & 7) ^ (n & 7));
    glds16(src + (n << 9) + (g << 3), ldsbuf + (gi << 3));
  }
}

// ---------------- fused main kernel ----------------
// grid = 256 (64-row m-tiles, FULL H=256 per block), 512 threads = 8 waves (2x4).
// A (xv) lives in registers (bf16 frags, loaded once from f32 global).
// Gate computed in-prologue via hi/lo-split MFMA + 8-lane softmax.
// Expert loop streams only B (We) through a double-buffered swizzled LDS chunk.
// Epilogue: comb -> LDS bf16 -> tower MFMA -> sigmoid -> out.
// NOTE launch_bounds (512, 1): 1 block/CU -> 256-VGPR cap. (512,2) gave a
// 128-VGPR cap (CUDA blocks/CU semantics) -> ~100 regs spilled, 22 MB scratch.
__global__ __launch_bounds__(512, 1) void moe_main(
    const float* __restrict__ xv, const u16* __restrict__ We_bf,
    const float* __restrict__ be, const float* __restrict__ bg,
    const u16* __restrict__ Wg_hi, const u16* __restrict__ Wg_lo,
    const u16* __restrict__ Wt_bf, const float* __restrict__ bt,
    float* __restrict__ out) {
  __shared__ u16 lds[65536];            // 128 KB: two 64KB B buffers; reused for comb

  const int tid = threadIdx.x;
  const int lane = tid & 63;
  const int wid = tid >> 6;             // 0..7
  const int wm = wid >> 2;              // 0..1  (32-row band)
  const int wn = wid & 3;               // 0..3  (64-col band)
  const int l15 = lane & 15;
  const int l4 = lane >> 4;             // 0..3
  const int m0 = blockIdx.x << 6;

  // issue stage of chunk 0 (e=0,kc=0) into buf0 early — covered by prologue work
  stage_chunk(We_bf, lds, 0, tid);

  // ---- A load (f32 -> bf16 frags in regs) + gate logits via hi/lo MFMA ----
  // lv is per-iteration transient; unroll 4 keeps in-flight f32 loads bounded.
  bf16x8 ah[2][16];                     // 128 VGPR: 32 rows x K=512
  f32x4 gacc[2] = {{0.f,0.f,0.f,0.f},{0.f,0.f,0.f,0.f}};
  const int esrc = l15 & 7;
#pragma unroll
  for (int mt = 0; mt < 2; mt++) {
#pragma unroll 4
    for (int ks = 0; ks < 16; ks++) {
      const float* ap = xv + ((m0 + wm * 32 + mt * 16 + l15) << 9) + ks * 32 + l4 * 8;
      float4 xa = *(const float4*)ap;
      float4 xb = *(const float4*)(ap + 4);
      float x[8];
      x[0]=xa.x; x[1]=xa.y; x[2]=xa.z; x[3]=xa.w; x[4]=xb.x; x[5]=xb.y; x[6]=xb.z; x[7]=xb.w;
      bf16x8 hv, lv;
#pragma unroll
      for (int j = 0; j < 8; j++) {
        u16 hb_ = f2bf(x[j]);
        float hf = __builtin_bit_cast(float, ((unsigned)hb_) << 16);
        hv[j] = __builtin_bit_cast(__bf16, hb_);
        lv[j] = __builtin_bit_cast(__bf16, f2bf(x[j] - hf));
      }
      ah[mt][ks] = hv;
      bf16x8 wh = *(const bf16x8*)(Wg_hi + (esrc << 9) + ks * 32 + l4 * 8);
      bf16x8 wl = *(const bf16x8*)(Wg_lo + (esrc << 9) + ks * 32 + l4 * 8);
      gacc[mt] = __builtin_amdgcn_mfma_f32_16x16x32_bf16(hv, wh, gacc[mt], 0, 0, 0);
      gacc[mt] = __builtin_amdgcn_mfma_f32_16x16x32_bf16(lv, wh, gacc[mt], 0, 0, 0);
      gacc[mt] = __builtin_amdgcn_mfma_f32_16x16x32_bf16(hv, wl, gacc[mt], 0, 0, 0);
    }
  }
  // softmax over experts: lane holds logit[row=l4*4+i][e=l15&7]; reduce over 8-lane group
  float gv[2][4];
  {
    float bgv = bg[esrc];
#pragma unroll
    for (int mt = 0; mt < 2; mt++)
#pragma unroll
      for (int i = 0; i < 4; i++) {
        float z = gacc[mt][i] + bgv;
        float mx = z;
        mx = fmaxf(mx, __shfl_xor(mx, 1));
        mx = fmaxf(mx, __shfl_xor(mx, 2));
        mx = fmaxf(mx, __shfl_xor(mx, 4));
        float p = __expf(z - mx);
        float s = p;
        s += __shfl_xor(s, 1);
        s += __shfl_xor(s, 2);
        s += __shfl_xor(s, 4);
        gv[mt][i] = p / s;
      }
  }

  // ---- expert loop: B streams through LDS, A from regs ----
  f32x4 comb[2][4];
#pragma unroll
  for (int mt = 0; mt < 2; mt++)
#pragma unroll
    for (int nt = 0; nt < 4; nt++) comb[mt][nt] = {0.f, 0.f, 0.f, 0.f};

#pragma unroll 1
  for (int e = 0; e < 8; e++) {
    f32x4 acc[2][4];
#pragma unroll
    for (int mt = 0; mt < 2; mt++)
#pragma unroll
      for (int nt = 0; nt < 4; nt++) acc[mt][nt] = {0.f, 0.f, 0.f, 0.f};

#pragma unroll
    for (int kc = 0; kc < 4; kc++) {
      __syncthreads();                  // buf[kc&1] staged + prev reads done
      int t = e * 4 + kc + 1;
      if (t < 32) stage_chunk(We_bf, &lds[(((kc & 1) ^ 1) << 15)], t, tid);
      const u16* ldsB = &lds[((kc & 1) << 15)];
#pragma unroll
      for (int ks = 0; ks < 4; ks++) {
        const int gg = ks * 4 + l4;
        bf16x8 bfr[4];
#pragma unroll
        for (int nt = 0; nt < 4; nt++) {
          int n = wn * 64 + nt * 16 + l15;
          int slot = (gg & 8) | ((gg & 7) ^ (n & 7));
          bfr[nt] = *(const bf16x8*)&ldsB[(n << 7) + (slot << 3)];
        }
#pragma unroll
        for (int mt = 0; mt < 2; mt++)
#pragma unroll
          for (int nt = 0; nt < 4; nt++)
            acc[mt][nt] = __builtin_amdgcn_mfma_f32_16x16x32_bf16(
                ah[mt][kc * 4 + ks], bfr[nt], acc[mt][nt], 0, 0, 0);
      }
    }
    // fold: comb += gate[row,e] * relu(acc + be[e,h])   (reg-local, no barrier)
    float bev[4];
#pragma unroll
    for (int nt = 0; nt < 4; nt++)
      bev[nt] = be[(e << 8) + wn * 64 + nt * 16 + l15];
#pragma unroll
    for (int mt = 0; mt < 2; mt++)
#pragma unroll
      for (int i = 0; i < 4; i++) {
        float g = __shfl(gv[mt][i], (lane & 48) | e);
#pragma unroll
        for (int nt = 0; nt < 4; nt++)
          comb[mt][nt][i] += g * fmaxf(acc[mt][nt][i] + bev[nt], 0.f);
      }
  }

  // ---- tower: comb[64x256] (bf16 via LDS) x Wt^T -> sigmoid -> out ----
  __syncthreads();                      // all B reads done; reuse LDS for comb
#pragma unroll
  for (int mt = 0; mt < 2; mt++)
#pragma unroll
    for (int i = 0; i < 4; i++) {
      int row = wm * 32 + mt * 16 + l4 * 4 + i;
#pragma unroll
      for (int nt = 0; nt < 4; nt++) {
        int col = wn * 64 + nt * 16 + l15;
        __bf16 v = (__bf16)comb[mt][nt][i];
        lds[row * 264 + col] = __builtin_bit_cast(u16, v);   // pad 264
      }
    }
  __syncthreads();
  if (wid < 4) {
    f32x4 tacc[4];
#pragma unroll
    for (int nt = 0; nt < 4; nt++) tacc[nt] = {0.f, 0.f, 0.f, 0.f};
#pragma unroll
    for (int ks = 0; ks < 8; ks++) {
      bf16x8 aT = *(const bf16x8*)&lds[(wid * 16 + l15) * 264 + ks * 32 + l4 * 8];
#pragma unroll
      for (int nt = 0; nt < 4; nt++) {
        bf16x8 bT = *(const bf16x8*)&Wt_bf[(nt * 16 + l15) * 256 + ks * 32 + l4 * 8];
        tacc[nt] = __builtin_amdgcn_mfma_f32_16x16x32_bf16(aT, bT, tacc[nt], 0, 0, 0);
      }
    }
#pragma unroll
    for (int nt = 0; nt < 4; nt++) {
      float btv = bt[nt * 16 + l15];
#pragma unroll
      for (int i = 0; i < 4; i++) {
        int row = m0 + wid * 16 + l4 * 4 + i;
        float v = tacc[nt][i] + btv;
        out[row * 64 + nt * 16 + l15] = 1.f / (1.f + __expf(-v));
      }
    }
  }
}

extern "C" void kernel_launch(void* const* d_in, const int* in_sizes, int n_in,
                              void* d_out, int out_size, void* d_ws, size_t ws_size,
                              hipStream_t stream) {
  const float* xv = (const float*)d_in[0];
  const float* We = (const float*)d_in[1];
  const float* be = (const float*)d_in[2];
  const float* Wg = (const float*)d_in[3];
  const float* bg = (const float*)d_in[4];
  const float* Wt = (const float*)d_in[5];
  const float* bt = (const float*)d_in[6];

  char* ws = (char*)d_ws;
  u16* We_bf = (u16*)ws;                        // 2 MB   (8*256*512 bf16)
  u16* Wt_bf = (u16*)(ws + 2097152);            // 32 KB  (64*256 bf16)
  u16* Wg_hi = (u16*)(ws + 2129920);            // 8 KB   (8*512 bf16)
  u16* Wg_lo = (u16*)(ws + 2138112);            // 8 KB

  prep_w<<<522, 256, 0, stream>>>(We, Wt, Wg, We_bf, Wt_bf, Wg_hi, Wg_lo);
  moe_main<<<256, 512, 0, stream>>>(xv, We_bf, be, bg, Wg_hi, Wg_lo, Wt_bf, bt,
                                    (float*)d_out);
}

// Round 3
// 157.581 us; speedup vs baseline: 1.3610x; 1.3610x over previous
//
#include <hip/hip_runtime.h>
#include <hip/hip_bf16.h>
#include <stdint.h>

typedef unsigned short u16;
typedef __bf16 bf16x8 __attribute__((ext_vector_type(8)));
typedef float f32x4 __attribute__((ext_vector_type(4)));

// E=8, D=512, H=256, T=64, B=16384

__device__ __forceinline__ void glds16(const void* g, void* l) {
  __builtin_amdgcn_global_load_lds(
      (const __attribute__((address_space(1))) unsigned int*)g,
      (__attribute__((address_space(3))) unsigned int*)l, 16, 0, 0);
}

__device__ __forceinline__ u16 f2bf(float f) {
  unsigned int u = __builtin_bit_cast(unsigned int, f);
  u += 0x7fffu + ((u >> 16) & 1u);   // RNE (finite inputs)
  return (u16)(u >> 16);
}

// ---------------- prep: weight conversion only ----------------
__global__ __launch_bounds__(256) void prep_w(
    const float* __restrict__ We, const float* __restrict__ Wt,
    const float* __restrict__ Wg,
    u16* __restrict__ We_bf, u16* __restrict__ Wt_bf,
    u16* __restrict__ Wg_hi, u16* __restrict__ Wg_lo) {
  const int bx = blockIdx.x;
  if (bx < 520) {
    const float* src; u16* dst;
    if (bx < 512) { int base = bx * 2048 + threadIdx.x * 8; src = We + base; dst = We_bf + base; }
    else { int base = (bx - 512) * 2048 + threadIdx.x * 8; src = Wt + base; dst = Wt_bf + base; }
    float4 a = *(const float4*)src;
    float4 b = *(const float4*)(src + 4);
    uint4 o;
    o.x = (unsigned)f2bf(a.x) | ((unsigned)f2bf(a.y) << 16);
    o.y = (unsigned)f2bf(a.z) | ((unsigned)f2bf(a.w) << 16);
    o.z = (unsigned)f2bf(b.x) | ((unsigned)f2bf(b.y) << 16);
    o.w = (unsigned)f2bf(b.z) | ((unsigned)f2bf(b.w) << 16);
    *(uint4*)dst = o;
  } else {
    int base = (bx - 520) * 2048 + threadIdx.x * 8;
    float x[8];
    float4 a = *(const float4*)(Wg + base);
    float4 b = *(const float4*)(Wg + base + 4);
    x[0]=a.x; x[1]=a.y; x[2]=a.z; x[3]=a.w; x[4]=b.x; x[5]=b.y; x[6]=b.z; x[7]=b.w;
    u16 h[8], l[8];
#pragma unroll
    for (int j = 0; j < 8; j++) {
      h[j] = f2bf(x[j]);
      float hf = __builtin_bit_cast(float, ((unsigned)h[j]) << 16);
      l[j] = f2bf(x[j] - hf);
    }
    uint4 oh, ol;
    oh.x = (unsigned)h[0] | ((unsigned)h[1] << 16);
    oh.y = (unsigned)h[2] | ((unsigned)h[3] << 16);
    oh.z = (unsigned)h[4] | ((unsigned)h[5] << 16);
    oh.w = (unsigned)h[6] | ((unsigned)h[7] << 16);
    ol.x = (unsigned)l[0] | ((unsigned)l[1] << 16);
    ol.y = (unsigned)l[2] | ((unsigned)l[3] << 16);
    ol.z = (unsigned)l[4] | ((unsigned)l[5] << 16);
    ol.w = (unsigned)l[6] | ((unsigned)l[7] << 16);
    *(uint4*)(Wg_hi + base) = oh;
    *(uint4*)(Wg_lo + base) = ol;
  }
}

// stage one B chunk (256 h-rows x 128 k, bf16) into ldsbuf via glds16,
// 16B-granule xor-swizzled source (slot s of row n holds granule (s&8)|((s&7)^(n&7)))
__device__ __forceinline__ void stage_chunk(const u16* __restrict__ We_bf,
                                            u16* ldsbuf, int t, int tid) {
  const int e_ = t >> 2, kc_ = t & 3;
  const u16* src = We_bf + (e_ << 17) + (kc_ << 7);
#pragma unroll
  for (int r = 0; r < 8; r++) {
    int gi = r * 512 + tid;             // 0..4095
    int n = gi >> 4, s = gi & 15;
    int g = (s & 8) | ((s & 7) ^ (n & 7));
    glds16(src + (n << 9) + (g << 3), ldsbuf + (gi << 3));
  }
}

// ---------------- fused main kernel ----------------
// grid = 256 (64-row m-tiles, FULL H=256 per block), 512 threads = 8 waves (2x4).
// A (xv) lives in registers (bf16 frags, loaded once from f32 global).
// RULE #20: every ah[][] index must be a compile-time constant — all loops
// touching ah are FULLY unrolled. A partial unroll (round 2) sent the whole
// 128-VGPR array to scratch: 65 MB spill writes, 250 MB re-reads, 1.6x slower.
// launch_bounds (512,1): CUDA-style blocks/CU semantics observed -> 1 block/CU
// -> 2 waves/SIMD -> 256-VGPR cap. (512,2) capped at 128 and forced spill.
__global__ __launch_bounds__(512, 1) void moe_main(
    const float* __restrict__ xv, const u16* __restrict__ We_bf,
    const float* __restrict__ be, const float* __restrict__ bg,
    const u16* __restrict__ Wg_hi, const u16* __restrict__ Wg_lo,
    const u16* __restrict__ Wt_bf, const float* __restrict__ bt,
    float* __restrict__ out) {
  __shared__ u16 lds[65536];            // 128 KB: two 64KB B buffers; reused for comb

  const int tid = threadIdx.x;
  const int lane = tid & 63;
  const int wid = tid >> 6;             // 0..7
  const int wm = wid >> 2;              // 0..1  (32-row band)
  const int wn = wid & 3;               // 0..3  (64-col band)
  const int l15 = lane & 15;
  const int l4 = lane >> 4;             // 0..3
  const int m0 = blockIdx.x << 6;

  // issue stage of chunk 0 (e=0,kc=0) into buf0 early — covered by prologue work
  stage_chunk(We_bf, lds, 0, tid);

  // ---- A load (f32 -> bf16 frags in regs) + gate logits via hi/lo MFMA ----
  bf16x8 ah[2][16];                     // 128 VGPR: 32 rows x K=512
  f32x4 gacc[2] = {{0.f,0.f,0.f,0.f},{0.f,0.f,0.f,0.f}};
  const int esrc = l15 & 7;
#pragma unroll
  for (int mt = 0; mt < 2; mt++) {
#pragma unroll
    for (int ks = 0; ks < 16; ks++) {   // FULL unroll: ah index stays constant
      const float* ap = xv + ((m0 + wm * 32 + mt * 16 + l15) << 9) + ks * 32 + l4 * 8;
      float4 xa = *(const float4*)ap;
      float4 xb = *(const float4*)(ap + 4);
      float x[8];
      x[0]=xa.x; x[1]=xa.y; x[2]=xa.z; x[3]=xa.w; x[4]=xb.x; x[5]=xb.y; x[6]=xb.z; x[7]=xb.w;
      bf16x8 hv, lv;
#pragma unroll
      for (int j = 0; j < 8; j++) {
        u16 hb_ = f2bf(x[j]);
        float hf = __builtin_bit_cast(float, ((unsigned)hb_) << 16);
        hv[j] = __builtin_bit_cast(__bf16, hb_);
        lv[j] = __builtin_bit_cast(__bf16, f2bf(x[j] - hf));
      }
      ah[mt][ks] = hv;
      bf16x8 wh = *(const bf16x8*)(Wg_hi + (esrc << 9) + ks * 32 + l4 * 8);
      bf16x8 wl = *(const bf16x8*)(Wg_lo + (esrc << 9) + ks * 32 + l4 * 8);
      gacc[mt] = __builtin_amdgcn_mfma_f32_16x16x32_bf16(hv, wh, gacc[mt], 0, 0, 0);
      gacc[mt] = __builtin_amdgcn_mfma_f32_16x16x32_bf16(lv, wh, gacc[mt], 0, 0, 0);
      gacc[mt] = __builtin_amdgcn_mfma_f32_16x16x32_bf16(hv, wl, gacc[mt], 0, 0, 0);
    }
  }
  // softmax over experts: lane holds logit[row=l4*4+i][e=l15&7]; reduce over 8-lane group
  float gv[2][4];
  {
    float bgv = bg[esrc];
#pragma unroll
    for (int mt = 0; mt < 2; mt++)
#pragma unroll
      for (int i = 0; i < 4; i++) {
        float z = gacc[mt][i] + bgv;
        float mx = z;
        mx = fmaxf(mx, __shfl_xor(mx, 1));
        mx = fmaxf(mx, __shfl_xor(mx, 2));
        mx = fmaxf(mx, __shfl_xor(mx, 4));
        float p = __expf(z - mx);
        float s = p;
        s += __shfl_xor(s, 1);
        s += __shfl_xor(s, 2);
        s += __shfl_xor(s, 4);
        gv[mt][i] = p / s;
      }
  }

  // ---- expert loop: B streams through LDS, A from regs ----
  f32x4 comb[2][4];
#pragma unroll
  for (int mt = 0; mt < 2; mt++)
#pragma unroll
    for (int nt = 0; nt < 4; nt++) comb[mt][nt] = {0.f, 0.f, 0.f, 0.f};

#pragma unroll 1
  for (int e = 0; e < 8; e++) {
    f32x4 acc[2][4];
#pragma unroll
    for (int mt = 0; mt < 2; mt++)
#pragma unroll
      for (int nt = 0; nt < 4; nt++) acc[mt][nt] = {0.f, 0.f, 0.f, 0.f};

#pragma unroll
    for (int kc = 0; kc < 4; kc++) {    // FULL unroll: ah index stays constant
      __syncthreads();                  // buf[kc&1] staged + prev reads done
      int t = e * 4 + kc + 1;
      if (t < 32) stage_chunk(We_bf, &lds[(((kc & 1) ^ 1) << 15)], t, tid);
      const u16* ldsB = &lds[((kc & 1) << 15)];
#pragma unroll
      for (int ks = 0; ks < 4; ks++) {
        const int gg = ks * 4 + l4;
        bf16x8 bfr[4];
#pragma unroll
        for (int nt = 0; nt < 4; nt++) {
          int n = wn * 64 + nt * 16 + l15;
          int slot = (gg & 8) | ((gg & 7) ^ (n & 7));
          bfr[nt] = *(const bf16x8*)&ldsB[(n << 7) + (slot << 3)];
        }
#pragma unroll
        for (int mt = 0; mt < 2; mt++)
#pragma unroll
          for (int nt = 0; nt < 4; nt++)
            acc[mt][nt] = __builtin_amdgcn_mfma_f32_16x16x32_bf16(
                ah[mt][kc * 4 + ks], bfr[nt], acc[mt][nt], 0, 0, 0);
      }
    }
    // fold: comb += gate[row,e] * relu(acc + be[e,h])   (reg-local, no barrier)
    float bev[4];
#pragma unroll
    for (int nt = 0; nt < 4; nt++)
      bev[nt] = be[(e << 8) + wn * 64 + nt * 16 + l15];
#pragma unroll
    for (int mt = 0; mt < 2; mt++)
#pragma unroll
      for (int i = 0; i < 4; i++) {
        float g = __shfl(gv[mt][i], (lane & 48) | e);
#pragma unroll
        for (int nt = 0; nt < 4; nt++)
          comb[mt][nt][i] += g * fmaxf(acc[mt][nt][i] + bev[nt], 0.f);
      }
  }

  // ---- tower: comb[64x256] (bf16 via LDS) x Wt^T -> sigmoid -> out ----
  __syncthreads();                      // all B reads done; reuse LDS for comb
#pragma unroll
  for (int mt = 0; mt < 2; mt++)
#pragma unroll
    for (int i = 0; i < 4; i++) {
      int row = wm * 32 + mt * 16 + l4 * 4 + i;
#pragma unroll
      for (int nt = 0; nt < 4; nt++) {
        int col = wn * 64 + nt * 16 + l15;
        __bf16 v = (__bf16)comb[mt][nt][i];
        lds[row * 264 + col] = __builtin_bit_cast(u16, v);   // pad 264
      }
    }
  __syncthreads();
  if (wid < 4) {
    f32x4 tacc[4];
#pragma unroll
    for (int nt = 0; nt < 4; nt++) tacc[nt] = {0.f, 0.f, 0.f, 0.f};
#pragma unroll
    for (int ks = 0; ks < 8; ks++) {
      bf16x8 aT = *(const bf16x8*)&lds[(wid * 16 + l15) * 264 + ks * 32 + l4 * 8];
#pragma unroll
      for (int nt = 0; nt < 4; nt++) {
        bf16x8 bT = *(const bf16x8*)&Wt_bf[(nt * 16 + l15) * 256 + ks * 32 + l4 * 8];
        tacc[nt] = __builtin_amdgcn_mfma_f32_16x16x32_bf16(aT, bT, tacc[nt], 0, 0, 0);
      }
    }
#pragma unroll
    for (int nt = 0; nt < 4; nt++) {
      float btv = bt[nt * 16 + l15];
#pragma unroll
      for (int i = 0; i < 4; i++) {
        int row = m0 + wid * 16 + l4 * 4 + i;
        float v = tacc[nt][i] + btv;
        out[row * 64 + nt * 16 + l15] = 1.f / (1.f + __expf(-v));
      }
    }
  }
}

extern "C" void kernel_launch(void* const* d_in, const int* in_sizes, int n_in,
                              void* d_out, int out_size, void* d_ws, size_t ws_size,
                              hipStream_t stream) {
  const float* xv = (const float*)d_in[0];
  const float* We = (const float*)d_in[1];
  const float* be = (const float*)d_in[2];
  const float* Wg = (const float*)d_in[3];
  const float* bg = (const float*)d_in[4];
  const float* Wt = (const float*)d_in[5];
  const float* bt = (const float*)d_in[6];

  char* ws = (char*)d_ws;
  u16* We_bf = (u16*)ws;                        // 2 MB   (8*256*512 bf16)
  u16* Wt_bf = (u16*)(ws + 2097152);            // 32 KB  (64*256 bf16)
  u16* Wg_hi = (u16*)(ws + 2129920);            // 8 KB   (8*512 bf16)
  u16* Wg_lo = (u16*)(ws + 2138112);            // 8 KB

  prep_w<<<522, 256, 0, stream>>>(We, Wt, Wg, We_bf, Wt_bf, Wg_hi, Wg_lo);
  moe_main<<<256, 512, 0, stream>>>(xv, We_bf, be, bg, Wg_hi, Wg_lo, Wt_bf, bt,
                                    (float*)d_out);
}